// Round 8
// baseline (534.851 us; speedup 1.0000x reference)
//
#include <hip/hip_runtime.h>

#define CN 2000
#define DF 2048
#define NS 20000
#define NBLK 250
#define NGRP 25
#define GRPSZ 10

typedef __attribute__((ext_vector_type(4))) float          f32x4;
typedef __attribute__((ext_vector_type(4))) int            i32x4;
typedef __attribute__((ext_vector_type(4))) unsigned short u16x4;

__device__ __forceinline__ float wredSum(float v){
#pragma unroll
  for (int o = 32; o >= 1; o >>= 1) v += __shfl_xor(v, o, 64);
  return v;
}
__device__ __forceinline__ float wredMax(float v){
#pragma unroll
  for (int o = 32; o >= 1; o >>= 1) v = fmaxf(v, __shfl_xor(v, o, 64));
  return v;
}
__device__ __forceinline__ unsigned short bfbits(float x){
  union { float f; unsigned u; } c; c.f = x;
  return (unsigned short)((c.u + 0x7fffu + ((c.u >> 16) & 1u)) >> 16);
}
__device__ __forceinline__ void gload16(const void* g, void* lds){
  __builtin_amdgcn_global_load_lds((const __attribute__((address_space(1))) unsigned int*)g,
      (__attribute__((address_space(3))) unsigned int*)lds, 16, 0, 0);
}

// Fence-free monotonic hierarchical grid barrier (agent-scope atomics only;
// no L2 wb/inv). bar[0]=root, bar[32]=generation, bar[64+g*32]=group counters.
// Cross-block data must move via agent-scope atomics; the leading
// s_waitcnt vmcnt(0) drains each thread's own stores before arrival.
__device__ __forceinline__ void gbar(int* bar, int target){
  asm volatile("s_waitcnt vmcnt(0)" ::: "memory");
  __syncthreads();
  if (threadIdx.x == 0){
    int g = blockIdx.x / GRPSZ;
    int prev = __hip_atomic_fetch_add(&bar[64 + g * 32], 1,
                  __ATOMIC_RELAXED, __HIP_MEMORY_SCOPE_AGENT);
    if (prev == target * GRPSZ - 1){
      int rp = __hip_atomic_fetch_add(&bar[0], 1,
                  __ATOMIC_RELAXED, __HIP_MEMORY_SCOPE_AGENT);
      if (rp == target * NGRP - 1){
        __hip_atomic_store(&bar[32], target, __ATOMIC_RELAXED, __HIP_MEMORY_SCOPE_AGENT);
      }
    }
    while (__hip_atomic_load(&bar[32], __ATOMIC_RELAXED, __HIP_MEMORY_SCOPE_AGENT) < target){
      __builtin_amdgcn_s_sleep(1);
    }
  }
  __syncthreads();
}

__global__ void k_zero(int* p, int n, int* bar){
  int i = blockIdx.x * 256 + threadIdx.x;
  if (i < n) p[i] = 0;
  if (i < 1024) bar[i] = 0;
}

__global__ void k_hist(const int* __restrict__ rgb, const int* __restrict__ iri,
                       int* cv, int* ci){
  int i = blockIdx.x * 256 + threadIdx.x;
  if (i < NS) atomicAdd(&cv[rgb[i]], 1);
  else if (i < 2 * NS) atomicAdd(&ci[iri[i - NS]], 1);
}

__global__ __launch_bounds__(1024) void k_scan(const int* __restrict__ cv, const int* __restrict__ ci,
                                               int* ov, int* oi){
  __shared__ int s[2048];
  int t = threadIdx.x;
  for (int pass = 0; pass < 2; ++pass){
    const int* c = pass ? ci : cv;
    int* o = pass ? oi : ov;
    s[t] = (t < CN) ? c[t] : 0;
    s[t + 1024] = (t + 1024 < CN) ? c[t + 1024] : 0;
    __syncthreads();
    for (int off = 1; off < 2048; off <<= 1){
      int a = (t >= off) ? s[t - off] : 0;
      int b = (t + 1024 >= off) ? s[t + 1024 - off] : 0;
      __syncthreads();
      s[t] += a; s[t + 1024] += b;
      __syncthreads();
    }
    if (t < CN) o[t] = s[t] - c[t];
    if (t + 1024 < CN) o[t + 1024] = s[t + 1024] - c[t + 1024];
    __syncthreads();
  }
}

__global__ void k_scatter(const int* __restrict__ rgb, const int* __restrict__ iri,
                          const int* __restrict__ ov, const int* __restrict__ oi,
                          int* curv, int* curi, int* ordv, int* ordi){
  int i = blockIdx.x * 256 + threadIdx.x;
  if (i < NS){
    int l = rgb[i];
    int p = atomicAdd(&curv[l], 1);
    ordv[ov[l] + p] = i;
  } else if (i < 2 * NS){
    int k = i - NS;
    int l = iri[k];
    int p = atomicAdd(&curi[l], 1);
    ordi[oi[l] + p] = k;
  }
}

// Blocks [0, 2*CN): one block per (modality,class) — softmax+proto+entropy.
// Blocks [2*CN, 2*CN+1000): f32->bf16 conversion + row-norm (old k_conv).
// NOTE: vmb/imb live in o5/o1 (dead until k_post / k_tr) — NOT o2/o3, which
// hold proto until k_prep consumes them.
__global__ __launch_bounds__(256) void k_class(const float* __restrict__ visl, const float* __restrict__ irl,
    const int* __restrict__ cv, const int* __restrict__ ci,
    const int* __restrict__ ov, const int* __restrict__ oi,
    const int* __restrict__ ordv, const int* __restrict__ ordi,
    float* __restrict__ pv, float* __restrict__ pi_,
    float* __restrict__ ev, float* __restrict__ ei,
    const float* __restrict__ vm, const float* __restrict__ im,
    unsigned short* __restrict__ vmb, unsigned short* __restrict__ imb,
    float* __restrict__ rv, float* __restrict__ ri){
  if (blockIdx.x >= 2 * CN){
    int g = (blockIdx.x - 2 * CN) * 256 + threadIdx.x;
    int wid = g >> 6, l = g & 63;
    if (wid >= 2 * CN) return;
    const float* src = (wid < CN) ? vm : im;
    unsigned short* dst = (wid < CN) ? vmb : imb;
    int r = (wid < CN) ? wid : wid - CN;
    const f32x4* row = (const f32x4*)(src + (size_t)r * DF);
    float s = 0.f;
#pragma unroll
    for (int k = 0; k < 8; ++k){
      int idx = l + k * 64;
      f32x4 vv = row[idx];
      s += vv[0]*vv[0] + vv[1]*vv[1] + vv[2]*vv[2] + vv[3]*vv[3];
      u16x4 o;
      o[0] = bfbits(vv[0]); o[1] = bfbits(vv[1]); o[2] = bfbits(vv[2]); o[3] = bfbits(vv[3]);
      *(u16x4*)(dst + (size_t)r * DF + idx * 4) = o;
    }
    s = wredSum(s);
    if (l == 0) ((wid < CN) ? rv : ri)[r] = 1.f / fmaxf(sqrtf(s), 1e-12f);
    return;
  }
  __shared__ __attribute__((aligned(16))) float acc4[4][2048];
  __shared__ int mem[128];
  __shared__ float red[4];
  int t = threadIdx.x, w = t >> 6, l = t & 63;
  bool ir = (blockIdx.x >= CN);
  int c = ir ? blockIdx.x - CN : blockIdx.x;
  const float* logits = ir ? irl : visl;
  int n = (ir ? ci : cv)[c];
  int base = (ir ? oi : ov)[c];
  const int* ord = ir ? ordi : ordv;
  float* proto = ir ? pi_ : pv;
  float* ent = ir ? ei : ev;
  bool useL = (n <= 128);
  for (int m = t; m < n && m < 128; m += 256) mem[m] = ord[base + m];
  for (int j = t; j < 2048; j += 256){
    acc4[0][j] = 0.f; acc4[1][j] = 0.f; acc4[2][j] = 0.f; acc4[3][j] = 0.f;
  }
  __syncthreads();
  if (t == 0 && useL){  // deterministic member order across replays
    for (int a = 1; a < n; ++a){
      int key = mem[a]; int b = a - 1;
      while (b >= 0 && mem[b] > key){ mem[b + 1] = mem[b]; --b; }
      mem[b + 1] = key;
    }
  }
  __syncthreads();
  for (int m = w; m < n; m += 4){
    int sidx = useL ? mem[m] : ord[base + m];
    const f32x4* row = (const f32x4*)(logits + (size_t)sidx * CN);
    f32x4 x[8]; float mx = -3.0e38f;
#pragma unroll
    for (int k = 0; k < 8; ++k){
      int idx = l + k * 64;
      f32x4 vv = {-3.0e38f, -3.0e38f, -3.0e38f, -3.0e38f};
      if (idx < 500) vv = row[idx];
      x[k] = vv;
      mx = fmaxf(mx, fmaxf(fmaxf(vv[0], vv[1]), fmaxf(vv[2], vv[3])));
    }
    mx = wredMax(mx);
    float sm = 0.f;
#pragma unroll
    for (int k = 0; k < 8; ++k){
      int idx = l + k * 64;
      if (idx < 500){
        f32x4 e;
        e[0] = expf(x[k][0] - mx); e[1] = expf(x[k][1] - mx);
        e[2] = expf(x[k][2] - mx); e[3] = expf(x[k][3] - mx);
        x[k] = e;
        sm += e[0] + e[1] + e[2] + e[3];
      }
    }
    sm = wredSum(sm);
    float inv = 1.f / sm;
#pragma unroll
    for (int k = 0; k < 8; ++k){
      int idx = l + k * 64;
      if (idx < 500){
        f32x4* a = (f32x4*)&acc4[w][idx * 4];
        f32x4 cur = *a;
        cur[0] += x[k][0] * inv; cur[1] += x[k][1] * inv;
        cur[2] += x[k][2] * inv; cur[3] += x[k][3] * inv;
        *a = cur;
      }
    }
  }
  __syncthreads();
  float invc = 1.f / fmaxf((float)n, 1.f);
  float el = 0.f;
  for (int j = t; j < CN; j += 256){
    float p = (acc4[0][j] + acc4[1][j] + acc4[2][j] + acc4[3][j]) * invc;
    proto[(size_t)c * CN + j] = p;
    p = fmaxf(p, 1e-12f);
    el -= p * logf(p);
  }
  el = wredSum(el);
  if (l == 0) red[w] = el;
  __syncthreads();
  if (t == 0) ent[c] = red[0] + red[1] + red[2] + red[3];
}

// E[i][j] = active ? exp(-(0.45*(1-pred) + 0.15*(1-conf))/0.07) : 0
__global__ __launch_bounds__(256) void k_prep(const float* __restrict__ pv, const float* __restrict__ pi_,
    const float* __restrict__ ev, const float* __restrict__ ei,
    const int* __restrict__ cv, const int* __restrict__ ci, float* __restrict__ E){
  __shared__ float s[64][65];
  int t = threadIdx.x;
  int i0 = blockIdx.y * 64, j0 = blockIdx.x * 64;
#pragma unroll
  for (int rr = 0; rr < 4; ++rr){
    int jl = (t >> 4) + rr * 16;
    int ch = t & 15;
    int gj = j0 + jl;
    int gib = i0 + ch * 4;
    f32x4 vv = {0.f, 0.f, 0.f, 0.f};
    if (gj < CN){
      if (gib + 3 < CN) vv = *(const f32x4*)(pi_ + (size_t)gj * CN + gib);
      else {
        for (int q = 0; q < 4; ++q) if (gib + q < CN) vv[q] = pi_[(size_t)gj * CN + gib + q];
      }
    }
    s[ch*4+0][jl] = vv[0]; s[ch*4+1][jl] = vv[1]; s[ch*4+2][jl] = vv[2]; s[ch*4+3][jl] = vv[3];
  }
  __syncthreads();
#pragma unroll
  for (int rr = 0; rr < 4; ++rr){
    int il = (t >> 4) + rr * 16;
    int ch = t & 15;
    int gi = i0 + il;
    int gjb = j0 + ch * 4;
    if (gi >= CN) continue;
    f32x4 pvv = {0.f, 0.f, 0.f, 0.f};
    bool full = (gjb + 3 < CN);
    if (full) pvv = *(const f32x4*)(pv + (size_t)gi * CN + gjb);
    else { for (int q = 0; q < 4; ++q) if (gjb + q < CN) pvv[q] = pv[(size_t)gi * CN + gjb + q]; }
    float evi = ev[gi];
    bool avi = cv[gi] > 0;
    f32x4 o;
#pragma unroll
    for (int q = 0; q < 4; ++q){
      int gj = gjb + q;
      if (gj >= CN){ o[q] = 0.f; continue; }
      float pred = 0.5f * (pvv[q] + s[il][ch*4+q]);
      float conf = fminf(fmaxf(1.f - (evi + ei[gj]) / 15.201804919084164f, 0.f), 1.f);
      float base = 0.45f * (1.f - pred) + 0.15f * (1.f - conf);
      bool act = avi && (ci[gj] > 0);
      o[q] = act ? expf(-base / 0.07f) : 0.f;
    }
    if (full) *(f32x4*)(E + (size_t)gi * CN + gjb) = o;
    else { for (int q = 0; q < 4; ++q) if (gjb + q < CN) E[(size_t)gi * CN + gjb + q] = o[q]; }
  }
}

// bf16 MFMA GEMM, 128x128 tile, BK=64, global_load_lds staging with XOR swizzle.
__global__ __launch_bounds__(256) void k_gemm2(const unsigned short* __restrict__ Ag,
    const unsigned short* __restrict__ Bg, const float* __restrict__ rv,
    const float* __restrict__ ri, const float* __restrict__ E, float* __restrict__ Km){
  __shared__ __attribute__((aligned(16))) unsigned short As[128 * 64];
  __shared__ __attribute__((aligned(16))) unsigned short Bs[128 * 64];
  int t = threadIdx.x, w = t >> 6, l = t & 63;
  int i0 = blockIdx.y * 128, j0 = blockIdx.x * 128;
  int wm = w >> 1, wn = w & 1;
  int srow8 = l >> 3, sch = l & 7;
  int lr = l & 15, hk = l >> 4;
  f32x4 z = {0.f, 0.f, 0.f, 0.f};
  f32x4 acc[4][4];
#pragma unroll
  for (int a = 0; a < 4; ++a)
#pragma unroll
    for (int b = 0; b < 4; ++b) acc[a][b] = z;

  for (int kt = 0; kt < DF / 64; ++kt){
    int k0 = kt * 64;
#pragma unroll
    for (int c2 = 0; c2 < 4; ++c2){
      int rbase = c2 * 32 + w * 8;
      int row = rbase + srow8;
      int lch = sch ^ (srow8 & 7);
      int gi = i0 + row; if (gi > CN - 1) gi = CN - 1;
      int gj = j0 + row; if (gj > CN - 1) gj = CN - 1;
      gload16(Ag + (size_t)gi * DF + k0 + lch * 8, &As[rbase * 64]);
      gload16(Bg + (size_t)gj * DF + k0 + lch * 8, &Bs[rbase * 64]);
    }
    __syncthreads();
#pragma unroll
    for (int s2 = 0; s2 < 2; ++s2){
      i32x4 af[4], bf[4];
#pragma unroll
      for (int f2 = 0; f2 < 4; ++f2){
        int ar = wm * 64 + f2 * 16 + lr;
        int ac = (s2 * 4 + hk) ^ (ar & 7);
        af[f2] = *(const i32x4*)&As[ar * 64 + ac * 8];
        int br = wn * 64 + f2 * 16 + lr;
        int bc = (s2 * 4 + hk) ^ (br & 7);
        bf[f2] = *(const i32x4*)&Bs[br * 64 + bc * 8];
      }
#pragma unroll
      for (int a = 0; a < 4; ++a)
#pragma unroll
        for (int b = 0; b < 4; ++b)
          asm volatile("v_mfma_f32_16x16x32_bf16 %0, %1, %2, %0"
                       : "+v"(acc[a][b]) : "v"(af[a]), "v"(bf[b]));
    }
    __syncthreads();
  }
#pragma unroll
  for (int a = 0; a < 4; ++a){
    int ib = i0 + wm * 64 + a * 16 + hk * 4;
#pragma unroll
    for (int b = 0; b < 4; ++b){
      int j = j0 + wn * 64 + b * 16 + lr;
      if (j < CN){
        float rij = ri[j];
#pragma unroll
        for (int q = 0; q < 4; ++q){
          int i = ib + q;
          if (i < CN){
            float dot = acc[a][b][q] * rv[i] * rij;
            float feat = fminf(fmaxf((dot + 1.f) * 0.5f, 0.f), 1.f);
            float kv = E[(size_t)i * CN + j] * expf(-0.4f * (1.f - feat) / 0.07f);
            Km[(size_t)i * CN + j] = kv;
          }
        }
      }
    }
  }
}

// 64x64 LDS transpose: KT = Km^T (overwrites imb — safe, gemm2 already done)
__global__ __launch_bounds__(256) void k_tr(const float* __restrict__ Km, float* __restrict__ KT){
  __shared__ float s[64][65];
  int t = threadIdx.x;
  int i0 = blockIdx.y * 64, j0 = blockIdx.x * 64;
#pragma unroll
  for (int rr = 0; rr < 4; ++rr){
    int il = (t >> 4) + rr * 16;
    int ch = t & 15;
    int gi = i0 + il, gjb = j0 + ch * 4;
    f32x4 vv = {0.f, 0.f, 0.f, 0.f};
    if (gi < CN){
      if (gjb + 3 < CN) vv = *(const f32x4*)(Km + (size_t)gi * CN + gjb);
      else { for (int q = 0; q < 4; ++q) if (gjb + q < CN) vv[q] = Km[(size_t)gi * CN + gjb + q]; }
    }
    s[ch*4+0][il] = vv[0]; s[ch*4+1][il] = vv[1]; s[ch*4+2][il] = vv[2]; s[ch*4+3][il] = vv[3];
  }
  __syncthreads();
#pragma unroll
  for (int rr = 0; rr < 4; ++rr){
    int jl = (t >> 4) + rr * 16;
    int ch = t & 15;
    int gj = j0 + jl, gib = i0 + ch * 4;
    if (gj >= CN) continue;
    f32x4 o;
    o[0] = s[jl][ch*4+0]; o[1] = s[jl][ch*4+1]; o[2] = s[jl][ch*4+2]; o[3] = s[jl][ch*4+3];
    if (gib + 3 < CN) *(f32x4*)(KT + (size_t)gj * CN + gib) = o;
    else { for (int q = 0; q < 4; ++q) if (gib + q < CN) KT[(size_t)gj * CN + gib + q] = o[q]; }
  }
}

#define ROWDOTS(M, X0, X1) do { \
  _Pragma("unroll") \
  for (int r_ = 0; r_ < 8; ++r_){ \
    f32x4 a_ = M[r_][0], b_ = M[r_][1]; \
    float s_ = a_[0]*(X0)[0]+a_[1]*(X0)[1]+a_[2]*(X0)[2]+a_[3]*(X0)[3] \
             + b_[0]*(X1)[0]+b_[1]*(X1)[1]+b_[2]*(X1)[2]+b_[3]*(X1)[3]; \
    s_ = wredSum(s_); \
    if (l == 0) part[w][r_] = s_; \
  } \
} while(0)

#define LOADCHUNK(G, X0, X1) do { \
  if (cok){ \
    _Pragma("unroll") \
    for (int q_ = 0; q_ < 4; ++q_) (X0)[q_] = __hip_atomic_load(&(G)[c0+q_], __ATOMIC_RELAXED, __HIP_MEMORY_SCOPE_AGENT); \
    _Pragma("unroll") \
    for (int q_ = 0; q_ < 4; ++q_) (X1)[q_] = __hip_atomic_load(&(G)[c0+4+q_], __ATOMIC_RELAXED, __HIP_MEMORY_SCOPE_AGENT); \
  } else { (X0) = z4; (X1) = z4; } \
} while(0)

// Persistent Sinkhorn: 250 blocks x 256, fence-free barriers, no LDS staging.
// Block b owns rows R..R+7 of K and KT; wave w owns columns [512w,512w+512).
// Per half-step each lane loads its 8 fresh-vector elements directly (agent
// scope) and partial dots combine via a 4x8 LDS reduce. 60 barriers.
__global__ __launch_bounds__(256, 1) void k_sink(
    const float* __restrict__ Km, const float* __restrict__ KTm,
    const int* __restrict__ cv, const int* __restrict__ ci,
    float* __restrict__ u_g, float* __restrict__ v_g,
    float* __restrict__ o0, float* __restrict__ o1,
    float* __restrict__ rconf, float* __restrict__ cconf,
    int* __restrict__ rass, int* __restrict__ cass,
    int* bar){
  __shared__ float ab[16];
  __shared__ float part[4][8];
  __shared__ float uown[8], vown[8], fsh[8];
  __shared__ float amaxv[4][8];
  __shared__ int amaxi[4][8];
  int b = blockIdx.x, t = threadIdx.x, w = t >> 6, l = t & 63;
  int R = b * 8;
  int c0 = w * 512 + l * 8;
  bool cok = (c0 < CN);
  f32x4 z4 = {0.f, 0.f, 0.f, 0.f};
  if (t < 8) ab[t] = (float)cv[R + t] / 20000.0f;
  else if (t < 16) ab[t] = (float)ci[R + t - 8] / 20000.0f;
  f32x4 kA[8][2], kT[8][2];
#pragma unroll
  for (int r = 0; r < 8; ++r){
    if (cok){
      kA[r][0] = *(const f32x4*)(Km + (size_t)(R+r) * CN + c0);
      kA[r][1] = *(const f32x4*)(Km + (size_t)(R+r) * CN + c0 + 4);
      kT[r][0] = *(const f32x4*)(KTm + (size_t)(R+r) * CN + c0);
      kT[r][1] = *(const f32x4*)(KTm + (size_t)(R+r) * CN + c0 + 4);
    } else {
      kA[r][0] = z4; kA[r][1] = z4; kT[r][0] = z4; kT[r][1] = z4;
    }
  }
  // u1 = a / rowsum(K)  (v == 1; padded cols hold zeros)
  {
    f32x4 one = {1.f, 1.f, 1.f, 1.f};
    ROWDOTS(kA, one, one);
    __syncthreads();
    if (t < 8){
      float s = part[0][t] + part[1][t] + part[2][t] + part[3][t];
      float a = ab[t];
      float uu = (a > 0.f) ? a / (s + 1e-8f) : 0.f;
      uown[t] = uu;
      __hip_atomic_store(&u_g[R + t], uu, __ATOMIC_RELAXED, __HIP_MEMORY_SCOPE_AGENT);
    }
  }
  int tgt = 1;
  gbar(bar, tgt); ++tgt;
  f32x4 xu0, xu1, xv0, xv1;
  for (int it = 0; it < 30; ++it){
    LOADCHUNK(u_g, xu0, xu1);
    ROWDOTS(kT, xu0, xu1);
    __syncthreads();
    if (t < 8){
      float s = part[0][t] + part[1][t] + part[2][t] + part[3][t];
      float bb = ab[8 + t];
      float vv = (bb > 0.f) ? bb / (s + 1e-8f) : 0.f;
      vown[t] = vv;
      __hip_atomic_store(&v_g[R + t], vv, __ATOMIC_RELAXED, __HIP_MEMORY_SCOPE_AGENT);
    }
    gbar(bar, tgt); ++tgt;
    if (it < 29){
      LOADCHUNK(v_g, xv0, xv1);
      ROWDOTS(kA, xv0, xv1);
      __syncthreads();
      if (t < 8){
        float s = part[0][t] + part[1][t] + part[2][t] + part[3][t];
        float a = ab[t];
        float uu = (a > 0.f) ? a / (s + 1e-8f) : 0.f;
        uown[t] = uu;
        __hip_atomic_store(&u_g[R + t], uu, __ATOMIC_RELAXED, __HIP_MEMORY_SCOPE_AGENT);
      }
      gbar(bar, tgt); ++tgt;
    }
  }
  // final v chunk (xu still holds u30 chunk loaded at it=29)
  LOADCHUNK(v_g, xv0, xv1);
  // row outputs: row_t[r][:] = f_r * K[r][:] * v[:]
  ROWDOTS(kA, xv0, xv1);
  __syncthreads();
  if (t < 8){
    float s = part[0][t] + part[1][t] + part[2][t] + part[3][t];
    float uu = uown[t];
    fsh[t] = uu / fmaxf(uu * s, 1e-12f);
  }
  __syncthreads();
#pragma unroll
  for (int r = 0; r < 8; ++r){
    float f = fsh[r];
    float bm = -1e30f; int bi = 1 << 30;
    if (cok){
      f32x4 w0, w1;
#pragma unroll
      for (int q = 0; q < 4; ++q){ w0[q] = f * kA[r][0][q] * xv0[q]; w1[q] = f * kA[r][1][q] * xv1[q]; }
      *(f32x4*)(o0 + (size_t)(R+r) * CN + c0) = w0;
      *(f32x4*)(o0 + (size_t)(R+r) * CN + c0 + 4) = w1;
#pragma unroll
      for (int q = 0; q < 4; ++q) if (w0[q] > bm){ bm = w0[q]; bi = c0 + q; }
#pragma unroll
      for (int q = 0; q < 4; ++q) if (w1[q] > bm){ bm = w1[q]; bi = c0 + 4 + q; }
    }
#pragma unroll
    for (int o = 32; o >= 1; o >>= 1){
      float om = __shfl_xor(bm, o, 64); int oi2 = __shfl_xor(bi, o, 64);
      if (om > bm || (om == bm && oi2 < bi)){ bm = om; bi = oi2; }
    }
    if (l == 0){ amaxv[w][r] = bm; amaxi[w][r] = bi; }
  }
  __syncthreads();
  if (t < 8){
    float bm = amaxv[0][t]; int bi = amaxi[0][t];
#pragma unroll
    for (int q2 = 1; q2 < 4; ++q2){
      float om = amaxv[q2][t]; int oi2 = amaxi[q2][t];
      if (om > bm || (om == bm && oi2 < bi)){ bm = om; bi = oi2; }
    }
    rconf[R + t] = bm; rass[R + t] = bi;
  }
  __syncthreads();
  // col outputs: col_t[r][:] = g_r * KT[r][:] * u[:]
  ROWDOTS(kT, xu0, xu1);
  __syncthreads();
  if (t < 8){
    float s = part[0][t] + part[1][t] + part[2][t] + part[3][t];
    float vv = vown[t];
    fsh[t] = vv / fmaxf(vv * s, 1e-12f);
  }
  __syncthreads();
#pragma unroll
  for (int r = 0; r < 8; ++r){
    float f = fsh[r];
    float bm = -1e30f; int bi = 1 << 30;
    if (cok){
      f32x4 w0, w1;
#pragma unroll
      for (int q = 0; q < 4; ++q){ w0[q] = f * kT[r][0][q] * xu0[q]; w1[q] = f * kT[r][1][q] * xu1[q]; }
      *(f32x4*)(o1 + (size_t)(R+r) * CN + c0) = w0;
      *(f32x4*)(o1 + (size_t)(R+r) * CN + c0 + 4) = w1;
#pragma unroll
      for (int q = 0; q < 4; ++q) if (w0[q] > bm){ bm = w0[q]; bi = c0 + q; }
#pragma unroll
      for (int q = 0; q < 4; ++q) if (w1[q] > bm){ bm = w1[q]; bi = c0 + 4 + q; }
    }
#pragma unroll
    for (int o = 32; o >= 1; o >>= 1){
      float om = __shfl_xor(bm, o, 64); int oi2 = __shfl_xor(bi, o, 64);
      if (om > bm || (om == bm && oi2 < bi)){ bm = om; bi = oi2; }
    }
    if (l == 0){ amaxv[w][r] = bm; amaxi[w][r] = bi; }
  }
  __syncthreads();
  if (t < 8){
    float bm = amaxv[0][t]; int bi = amaxi[0][t];
#pragma unroll
    for (int q2 = 1; q2 < 4; ++q2){
      float om = amaxv[q2][t]; int oi2 = amaxi[q2][t];
      if (om > bm || (om == bm && oi2 < bi)){ bm = om; bi = oi2; }
    }
    cconf[R + t] = bm; cass[R + t] = bi;
  }
}

// Merged fill + topk: one block per row i. Zeros o2..o5 rows, writes common/
// specific, then scatters row-topk into o4 and col-topk into o5.
__global__ __launch_bounds__(256) void k_post(const float* __restrict__ rt, const float* __restrict__ ct,
    const int* __restrict__ cv, const int* __restrict__ ci,
    const float* __restrict__ rc, const float* __restrict__ cc,
    const int* __restrict__ ra, const int* __restrict__ ca,
    float* o2, float* o3, float* o4, float* o5){
  __shared__ float sv[256 * 3];
  __shared__ int si[256 * 3];
  int i = blockIdx.x, t = threadIdx.x;
  bool av = cv[i] > 0, ai = ci[i] > 0;
  float rcv = rc[i], ccv = cc[i];
  int aidx = ra[i];
  bool high = av && (rcv >= 0.55f);
  bool cm = high && (ca[aidx] == i);
  bool sp = high && !cm;
  bool remr = av && (rcv >= 0.25f) && (rcv < 0.55f);
  bool remc = ai && (ccv >= 0.25f) && (ccv < 0.55f);
  f32x4 z = {0.f, 0.f, 0.f, 0.f};
  f32x4* p2 = (f32x4*)(o2 + (size_t)i * CN);
  f32x4* p3 = (f32x4*)(o3 + (size_t)i * CN);
  f32x4* p4 = (f32x4*)(o4 + (size_t)i * CN);
  f32x4* p5 = (f32x4*)(o5 + (size_t)i * CN);
  const f32x4* rp = (const f32x4*)(rt + (size_t)i * CN);
  for (int c = t; c < 500; c += 256){
    p2[c] = z;
    p3[c] = sp ? rp[c] : z;
    p4[c] = z;
    p5[c] = z;
  }
  __syncthreads();
  if (t == 0 && cm) o2[(size_t)i * CN + aidx] = rcv;
  for (int pass = 0; pass < 2; ++pass){
    bool run = pass ? remc : remr;
    if (!run) continue;
    const float* M = pass ? ct : rt;
    float* o = pass ? o5 : o4;
    float v0 = -1.f, v1 = -1.f, v2 = -1.f;
    int i0 = 1 << 30, i1 = 1 << 30, i2 = 1 << 30;
    for (int k = 0; k < 8; ++k){
      int j = t + k * 256;
      if (j >= CN) break;
      float val = M[(size_t)i * CN + j];
      if (val > v0 || (val == v0 && j < i0)){ v2=v1; i2=i1; v1=v0; i1=i0; v0=val; i0=j; }
      else if (val > v1 || (val == v1 && j < i1)){ v2=v1; i2=i1; v1=val; i1=j; }
      else if (val > v2 || (val == v2 && j < i2)){ v2=val; i2=j; }
    }
    sv[t*3+0]=v0; sv[t*3+1]=v1; sv[t*3+2]=v2;
    si[t*3+0]=i0; si[t*3+1]=i1; si[t*3+2]=i2;
    __syncthreads();
    if (t == 0){
      float w0=-1.f, w1=-1.f, w2=-1.f; int j0=1<<30, j1=1<<30, j2=1<<30;
      for (int q = 0; q < 256 * 3; ++q){
        float val = sv[q]; int j = si[q];
        if (j >= CN) continue;
        if (val > w0 || (val == w0 && j < j0)){ w2=w1; j2=j1; w1=w0; j1=j0; w0=val; j0=j; }
        else if (val > w1 || (val == w1 && j < j1)){ w2=w1; j2=j1; w1=val; j1=j; }
        else if (val > w2 || (val == w2 && j < j2)){ w2=val; j2=j; }
      }
      o[(size_t)i * CN + j0] = w0;
      o[(size_t)i * CN + j1] = w1;
      o[(size_t)i * CN + j2] = w2;
    }
    __syncthreads();
  }
}

extern "C" void kernel_launch(void* const* d_in, const int* in_sizes, int n_in,
                              void* d_out, int out_size, void* d_ws, size_t ws_size,
                              hipStream_t stream){
  (void)in_sizes; (void)n_in; (void)out_size; (void)ws_size;
  const float* visl = (const float*)d_in[0];
  const float* irl  = (const float*)d_in[1];
  const float* vm   = (const float*)d_in[2];
  const float* im   = (const float*)d_in[3];
  const int* rgb    = (const int*)d_in[4];
  const int* iri    = (const int*)d_in[5];
  float* out = (float*)d_out;
  float* o0 = out;                 // Km  -> row_t (in place)
  float* o1 = out + 4000000;       // imb(bf16) -> KTm -> col_t (in place)
  float* o2 = out + 8000000;       // proto_v -> common_rm
  float* o3 = out + 12000000;      // proto_i -> specific_rm
  float* o4 = out + 16000000;      // E -> remain_rm
  float* o5 = out + 20000000;      // vmb(bf16) -> remain_col_rm
  char* sm = (char*)d_ws;
  float* ev   = (float*)(sm + 0);
  float* ei   = (float*)(sm + 8000);
  float* rv   = (float*)(sm + 16000);
  float* ri   = (float*)(sm + 24000);
  float* uvec = (float*)(sm + 32000);
  float* vvec = (float*)(sm + 40000);
  int* bar    = (int*)(sm + 48000);   // [0]=root, [32]=gen, [64+g*32]=groups
  float* rconf= (float*)(sm + 64000);
  float* cconf= (float*)(sm + 72000);
  int* rass = (int*)(sm + 80000);
  int* cass = (int*)(sm + 88000);
  int* cv   = (int*)(sm + 96000);
  int* ci   = (int*)(sm + 104000);
  int* ov   = (int*)(sm + 112000);
  int* oi   = (int*)(sm + 120000);
  int* curv = (int*)(sm + 128000);
  int* curi = (int*)(sm + 136000);
  int* ordv = (int*)(sm + 176000);
  int* ordi = (int*)(sm + 256000);
  unsigned short* vmb = (unsigned short*)o5;   // dead until k_post
  unsigned short* imb = (unsigned short*)o1;   // dead until k_tr (after gemm2)

  k_zero<<<47, 256, 0, stream>>>(cv, 12000, bar);  // cv..curi contiguous + barrier vars
  k_hist<<<157, 256, 0, stream>>>(rgb, iri, cv, ci);
  k_scan<<<1, 1024, 0, stream>>>(cv, ci, ov, oi);
  k_scatter<<<157, 256, 0, stream>>>(rgb, iri, ov, oi, curv, curi, ordv, ordi);
  k_class<<<2 * CN + 1000, 256, 0, stream>>>(visl, irl, cv, ci, ov, oi, ordv, ordi,
                                             o2, o3, ev, ei, vm, im, vmb, imb, rv, ri);
  k_prep<<<dim3(32, 32), 256, 0, stream>>>(o2, o3, ev, ei, cv, ci, o4);
  k_gemm2<<<dim3(16, 16), 256, 0, stream>>>(vmb, imb, rv, ri, o4, o0);
  k_tr<<<dim3(32, 32), 256, 0, stream>>>(o0, o1);
  k_sink<<<NBLK, 256, 0, stream>>>(o0, o1, cv, ci, uvec, vvec, o0, o1,
                                   rconf, cconf, rass, cass, bar);
  k_post<<<CN, 256, 0, stream>>>(o0, o1, cv, ci, rconf, cconf, rass, cass, o2, o3, o4, o5);
}

// Round 10
// 423.240 us; speedup vs baseline: 1.2637x; 1.2637x over previous
//
#include <hip/hip_runtime.h>

#define CN 2000
#define DF 2048
#define NS 20000
#define NBLK 125
#define NGRP 25
#define GRPSZ 5

typedef __attribute__((ext_vector_type(4))) float          f32x4;
typedef __attribute__((ext_vector_type(4))) int            i32x4;
typedef __attribute__((ext_vector_type(4))) unsigned short u16x4;

__device__ __forceinline__ float wredSum(float v){
#pragma unroll
  for (int o = 32; o >= 1; o >>= 1) v += __shfl_xor(v, o, 64);
  return v;
}
__device__ __forceinline__ float wredMax(float v){
#pragma unroll
  for (int o = 32; o >= 1; o >>= 1) v = fmaxf(v, __shfl_xor(v, o, 64));
  return v;
}
__device__ __forceinline__ unsigned short bfbits(float x){
  union { float f; unsigned u; } c; c.f = x;
  return (unsigned short)((c.u + 0x7fffu + ((c.u >> 16) & 1u)) >> 16);
}
__device__ __forceinline__ void gload16(const void* g, void* lds){
  __builtin_amdgcn_global_load_lds((const __attribute__((address_space(1))) unsigned int*)g,
      (__attribute__((address_space(3))) unsigned int*)lds, 16, 0, 0);
}

// Fence-free monotonic hierarchical grid barrier (agent-scope atomics only;
// no L2 wb/inv). bar[0]=root, bar[32]=generation, bar[64+g*32]=group counters.
// Cross-block data must move via agent-scope atomics; the leading
// s_waitcnt vmcnt(0) drains each thread's own stores before arrival.
__device__ __forceinline__ void gbar(int* bar, int target){
  asm volatile("s_waitcnt vmcnt(0)" ::: "memory");
  __syncthreads();
  if (threadIdx.x == 0){
    int g = blockIdx.x / GRPSZ;
    int prev = __hip_atomic_fetch_add(&bar[64 + g * 32], 1,
                  __ATOMIC_RELAXED, __HIP_MEMORY_SCOPE_AGENT);
    if (prev == target * GRPSZ - 1){
      int rp = __hip_atomic_fetch_add(&bar[0], 1,
                  __ATOMIC_RELAXED, __HIP_MEMORY_SCOPE_AGENT);
      if (rp == target * NGRP - 1){
        __hip_atomic_store(&bar[32], target, __ATOMIC_RELAXED, __HIP_MEMORY_SCOPE_AGENT);
      }
    }
    while (__hip_atomic_load(&bar[32], __ATOMIC_RELAXED, __HIP_MEMORY_SCOPE_AGENT) < target){
      __builtin_amdgcn_s_sleep(1);
    }
  }
  __syncthreads();
}

__global__ void k_zero(int* p, int n, int* bar){
  int i = blockIdx.x * 256 + threadIdx.x;
  if (i < n) p[i] = 0;
  if (i < 1024) bar[i] = 0;
}

__global__ void k_hist(const int* __restrict__ rgb, const int* __restrict__ iri,
                       int* cv, int* ci){
  int i = blockIdx.x * 256 + threadIdx.x;
  if (i < NS) atomicAdd(&cv[rgb[i]], 1);
  else if (i < 2 * NS) atomicAdd(&ci[iri[i - NS]], 1);
}

__global__ __launch_bounds__(1024) void k_scan(const int* __restrict__ cv, const int* __restrict__ ci,
                                               int* ov, int* oi){
  __shared__ int s[2048];
  int t = threadIdx.x;
  for (int pass = 0; pass < 2; ++pass){
    const int* c = pass ? ci : cv;
    int* o = pass ? oi : ov;
    s[t] = (t < CN) ? c[t] : 0;
    s[t + 1024] = (t + 1024 < CN) ? c[t + 1024] : 0;
    __syncthreads();
    for (int off = 1; off < 2048; off <<= 1){
      int a = (t >= off) ? s[t - off] : 0;
      int b = (t + 1024 >= off) ? s[t + 1024 - off] : 0;
      __syncthreads();
      s[t] += a; s[t + 1024] += b;
      __syncthreads();
    }
    if (t < CN) o[t] = s[t] - c[t];
    if (t + 1024 < CN) o[t + 1024] = s[t + 1024] - c[t + 1024];
    __syncthreads();
  }
}

__global__ void k_scatter(const int* __restrict__ rgb, const int* __restrict__ iri,
                          const int* __restrict__ ov, const int* __restrict__ oi,
                          int* curv, int* curi, int* ordv, int* ordi){
  int i = blockIdx.x * 256 + threadIdx.x;
  if (i < NS){
    int l = rgb[i];
    int p = atomicAdd(&curv[l], 1);
    ordv[ov[l] + p] = i;
  } else if (i < 2 * NS){
    int k = i - NS;
    int l = iri[k];
    int p = atomicAdd(&curi[l], 1);
    ordi[oi[l] + p] = k;
  }
}

// Blocks [0, 2*CN): one block per (modality,class) — softmax+proto+entropy.
// Blocks [2*CN, 2*CN+1000): f32->bf16 conversion + row-norm.
// vmb/imb live in o5/o1 (dead until k_post / k_tr).
__global__ __launch_bounds__(256) void k_class(const float* __restrict__ visl, const float* __restrict__ irl,
    const int* __restrict__ cv, const int* __restrict__ ci,
    const int* __restrict__ ov, const int* __restrict__ oi,
    const int* __restrict__ ordv, const int* __restrict__ ordi,
    float* __restrict__ pv, float* __restrict__ pi_,
    float* __restrict__ ev, float* __restrict__ ei,
    const float* __restrict__ vm, const float* __restrict__ im,
    unsigned short* __restrict__ vmb, unsigned short* __restrict__ imb,
    float* __restrict__ rv, float* __restrict__ ri){
  if (blockIdx.x >= 2 * CN){
    int g = (blockIdx.x - 2 * CN) * 256 + threadIdx.x;
    int wid = g >> 6, l = g & 63;
    if (wid >= 2 * CN) return;
    const float* src = (wid < CN) ? vm : im;
    unsigned short* dst = (wid < CN) ? vmb : imb;
    int r = (wid < CN) ? wid : wid - CN;
    const f32x4* row = (const f32x4*)(src + (size_t)r * DF);
    float s = 0.f;
#pragma unroll
    for (int k = 0; k < 8; ++k){
      int idx = l + k * 64;
      f32x4 vv = row[idx];
      s += vv[0]*vv[0] + vv[1]*vv[1] + vv[2]*vv[2] + vv[3]*vv[3];
      u16x4 o;
      o[0] = bfbits(vv[0]); o[1] = bfbits(vv[1]); o[2] = bfbits(vv[2]); o[3] = bfbits(vv[3]);
      *(u16x4*)(dst + (size_t)r * DF + idx * 4) = o;
    }
    s = wredSum(s);
    if (l == 0) ((wid < CN) ? rv : ri)[r] = 1.f / fmaxf(sqrtf(s), 1e-12f);
    return;
  }
  __shared__ __attribute__((aligned(16))) float acc4[4][2048];
  __shared__ int mem[128];
  __shared__ float red[4];
  int t = threadIdx.x, w = t >> 6, l = t & 63;
  bool ir = (blockIdx.x >= CN);
  int c = ir ? blockIdx.x - CN : blockIdx.x;
  const float* logits = ir ? irl : visl;
  int n = (ir ? ci : cv)[c];
  int base = (ir ? oi : ov)[c];
  const int* ord = ir ? ordi : ordv;
  float* proto = ir ? pi_ : pv;
  float* ent = ir ? ei : ev;
  bool useL = (n <= 128);
  for (int m = t; m < n && m < 128; m += 256) mem[m] = ord[base + m];
  for (int j = t; j < 2048; j += 256){
    acc4[0][j] = 0.f; acc4[1][j] = 0.f; acc4[2][j] = 0.f; acc4[3][j] = 0.f;
  }
  __syncthreads();
  if (t == 0 && useL){  // deterministic member order across replays
    for (int a = 1; a < n; ++a){
      int key = mem[a]; int b = a - 1;
      while (b >= 0 && mem[b] > key){ mem[b + 1] = mem[b]; --b; }
      mem[b + 1] = key;
    }
  }
  __syncthreads();
  for (int m = w; m < n; m += 4){
    int sidx = useL ? mem[m] : ord[base + m];
    const f32x4* row = (const f32x4*)(logits + (size_t)sidx * CN);
    f32x4 x[8]; float mx = -3.0e38f;
#pragma unroll
    for (int k = 0; k < 8; ++k){
      int idx = l + k * 64;
      f32x4 vv = {-3.0e38f, -3.0e38f, -3.0e38f, -3.0e38f};
      if (idx < 500) vv = row[idx];
      x[k] = vv;
      mx = fmaxf(mx, fmaxf(fmaxf(vv[0], vv[1]), fmaxf(vv[2], vv[3])));
    }
    mx = wredMax(mx);
    float sm = 0.f;
#pragma unroll
    for (int k = 0; k < 8; ++k){
      int idx = l + k * 64;
      if (idx < 500){
        f32x4 e;
        e[0] = expf(x[k][0] - mx); e[1] = expf(x[k][1] - mx);
        e[2] = expf(x[k][2] - mx); e[3] = expf(x[k][3] - mx);
        x[k] = e;
        sm += e[0] + e[1] + e[2] + e[3];
      }
    }
    sm = wredSum(sm);
    float inv = 1.f / sm;
#pragma unroll
    for (int k = 0; k < 8; ++k){
      int idx = l + k * 64;
      if (idx < 500){
        f32x4* a = (f32x4*)&acc4[w][idx * 4];
        f32x4 cur = *a;
        cur[0] += x[k][0] * inv; cur[1] += x[k][1] * inv;
        cur[2] += x[k][2] * inv; cur[3] += x[k][3] * inv;
        *a = cur;
      }
    }
  }
  __syncthreads();
  float invc = 1.f / fmaxf((float)n, 1.f);
  float el = 0.f;
  for (int j = t; j < CN; j += 256){
    float p = (acc4[0][j] + acc4[1][j] + acc4[2][j] + acc4[3][j]) * invc;
    proto[(size_t)c * CN + j] = p;
    p = fmaxf(p, 1e-12f);
    el -= p * logf(p);
  }
  el = wredSum(el);
  if (l == 0) red[w] = el;
  __syncthreads();
  if (t == 0) ent[c] = red[0] + red[1] + red[2] + red[3];
}

// E[i][j] = active ? exp(-(0.45*(1-pred) + 0.15*(1-conf))/0.07) : 0
__global__ __launch_bounds__(256) void k_prep(const float* __restrict__ pv, const float* __restrict__ pi_,
    const float* __restrict__ ev, const float* __restrict__ ei,
    const int* __restrict__ cv, const int* __restrict__ ci, float* __restrict__ E){
  __shared__ float s[64][65];
  int t = threadIdx.x;
  int i0 = blockIdx.y * 64, j0 = blockIdx.x * 64;
#pragma unroll
  for (int rr = 0; rr < 4; ++rr){
    int jl = (t >> 4) + rr * 16;
    int ch = t & 15;
    int gj = j0 + jl;
    int gib = i0 + ch * 4;
    f32x4 vv = {0.f, 0.f, 0.f, 0.f};
    if (gj < CN){
      if (gib + 3 < CN) vv = *(const f32x4*)(pi_ + (size_t)gj * CN + gib);
      else {
        for (int q = 0; q < 4; ++q) if (gib + q < CN) vv[q] = pi_[(size_t)gj * CN + gib + q];
      }
    }
    s[ch*4+0][jl] = vv[0]; s[ch*4+1][jl] = vv[1]; s[ch*4+2][jl] = vv[2]; s[ch*4+3][jl] = vv[3];
  }
  __syncthreads();
#pragma unroll
  for (int rr = 0; rr < 4; ++rr){
    int il = (t >> 4) + rr * 16;
    int ch = t & 15;
    int gi = i0 + il;
    int gjb = j0 + ch * 4;
    if (gi >= CN) continue;
    f32x4 pvv = {0.f, 0.f, 0.f, 0.f};
    bool full = (gjb + 3 < CN);
    if (full) pvv = *(const f32x4*)(pv + (size_t)gi * CN + gjb);
    else { for (int q = 0; q < 4; ++q) if (gjb + q < CN) pvv[q] = pv[(size_t)gi * CN + gjb + q]; }
    float evi = ev[gi];
    bool avi = cv[gi] > 0;
    f32x4 o;
#pragma unroll
    for (int q = 0; q < 4; ++q){
      int gj = gjb + q;
      if (gj >= CN){ o[q] = 0.f; continue; }
      float pred = 0.5f * (pvv[q] + s[il][ch*4+q]);
      float conf = fminf(fmaxf(1.f - (evi + ei[gj]) / 15.201804919084164f, 0.f), 1.f);
      float base = 0.45f * (1.f - pred) + 0.15f * (1.f - conf);
      bool act = avi && (ci[gj] > 0);
      o[q] = act ? expf(-base / 0.07f) : 0.f;
    }
    if (full) *(f32x4*)(E + (size_t)gi * CN + gjb) = o;
    else { for (int q = 0; q < 4; ++q) if (gjb + q < CN) E[(size_t)gi * CN + gjb + q] = o[q]; }
  }
}

// bf16 MFMA GEMM, 128x128 tile, BK=64, global_load_lds staging with XOR swizzle.
__global__ __launch_bounds__(256) void k_gemm2(const unsigned short* __restrict__ Ag,
    const unsigned short* __restrict__ Bg, const float* __restrict__ rv,
    const float* __restrict__ ri, const float* __restrict__ E, float* __restrict__ Km){
  __shared__ __attribute__((aligned(16))) unsigned short As[128 * 64];
  __shared__ __attribute__((aligned(16))) unsigned short Bs[128 * 64];
  int t = threadIdx.x, w = t >> 6, l = t & 63;
  int i0 = blockIdx.y * 128, j0 = blockIdx.x * 128;
  int wm = w >> 1, wn = w & 1;
  int srow8 = l >> 3, sch = l & 7;
  int lr = l & 15, hk = l >> 4;
  f32x4 z = {0.f, 0.f, 0.f, 0.f};
  f32x4 acc[4][4];
#pragma unroll
  for (int a = 0; a < 4; ++a)
#pragma unroll
    for (int b = 0; b < 4; ++b) acc[a][b] = z;

  for (int kt = 0; kt < DF / 64; ++kt){
    int k0 = kt * 64;
#pragma unroll
    for (int c2 = 0; c2 < 4; ++c2){
      int rbase = c2 * 32 + w * 8;
      int row = rbase + srow8;
      int lch = sch ^ (srow8 & 7);
      int gi = i0 + row; if (gi > CN - 1) gi = CN - 1;
      int gj = j0 + row; if (gj > CN - 1) gj = CN - 1;
      gload16(Ag + (size_t)gi * DF + k0 + lch * 8, &As[rbase * 64]);
      gload16(Bg + (size_t)gj * DF + k0 + lch * 8, &Bs[rbase * 64]);
    }
    __syncthreads();
#pragma unroll
    for (int s2 = 0; s2 < 2; ++s2){
      i32x4 af[4], bf[4];
#pragma unroll
      for (int f2 = 0; f2 < 4; ++f2){
        int ar = wm * 64 + f2 * 16 + lr;
        int ac = (s2 * 4 + hk) ^ (ar & 7);
        af[f2] = *(const i32x4*)&As[ar * 64 + ac * 8];
        int br = wn * 64 + f2 * 16 + lr;
        int bc = (s2 * 4 + hk) ^ (br & 7);
        bf[f2] = *(const i32x4*)&Bs[br * 64 + bc * 8];
      }
#pragma unroll
      for (int a = 0; a < 4; ++a)
#pragma unroll
        for (int b = 0; b < 4; ++b)
          asm volatile("v_mfma_f32_16x16x32_bf16 %0, %1, %2, %0"
                       : "+v"(acc[a][b]) : "v"(af[a]), "v"(bf[b]));
    }
    __syncthreads();
  }
#pragma unroll
  for (int a = 0; a < 4; ++a){
    int ib = i0 + wm * 64 + a * 16 + hk * 4;
#pragma unroll
    for (int b = 0; b < 4; ++b){
      int j = j0 + wn * 64 + b * 16 + lr;
      if (j < CN){
        float rij = ri[j];
#pragma unroll
        for (int q = 0; q < 4; ++q){
          int i = ib + q;
          if (i < CN){
            float dot = acc[a][b][q] * rv[i] * rij;
            float feat = fminf(fmaxf((dot + 1.f) * 0.5f, 0.f), 1.f);
            float kv = E[(size_t)i * CN + j] * expf(-0.4f * (1.f - feat) / 0.07f);
            Km[(size_t)i * CN + j] = kv;
          }
        }
      }
    }
  }
}

// 64x64 LDS transpose: KT = Km^T (overwrites imb — safe, gemm2 already done)
__global__ __launch_bounds__(256) void k_tr(const float* __restrict__ Km, float* __restrict__ KT){
  __shared__ float s[64][65];
  int t = threadIdx.x;
  int i0 = blockIdx.y * 64, j0 = blockIdx.x * 64;
#pragma unroll
  for (int rr = 0; rr < 4; ++rr){
    int il = (t >> 4) + rr * 16;
    int ch = t & 15;
    int gi = i0 + il, gjb = j0 + ch * 4;
    f32x4 vv = {0.f, 0.f, 0.f, 0.f};
    if (gi < CN){
      if (gjb + 3 < CN) vv = *(const f32x4*)(Km + (size_t)gi * CN + gjb);
      else { for (int q = 0; q < 4; ++q) if (gjb + q < CN) vv[q] = Km[(size_t)gi * CN + gjb + q]; }
    }
    s[ch*4+0][il] = vv[0]; s[ch*4+1][il] = vv[1]; s[ch*4+2][il] = vv[2]; s[ch*4+3][il] = vv[3];
  }
  __syncthreads();
#pragma unroll
  for (int rr = 0; rr < 4; ++rr){
    int jl = (t >> 4) + rr * 16;
    int ch = t & 15;
    int gj = j0 + jl, gib = i0 + ch * 4;
    if (gj >= CN) continue;
    f32x4 o;
    o[0] = s[jl][ch*4+0]; o[1] = s[jl][ch*4+1]; o[2] = s[jl][ch*4+2]; o[3] = s[jl][ch*4+3];
    if (gib + 3 < CN) *(f32x4*)(KT + (size_t)gj * CN + gib) = o;
    else { for (int q = 0; q < 4; ++q) if (gib + q < CN) KT[(size_t)gj * CN + gib + q] = o[q]; }
  }
}

#define STAGE(G, L) do { \
  float tmp_[4]; \
  _Pragma("unroll") \
  for (int k_ = 0; k_ < 4; ++k_){ \
    int idx_ = t + k_ * 512; \
    tmp_[k_] = (idx_ < CN) ? __hip_atomic_load(&(G)[idx_], __ATOMIC_RELAXED, __HIP_MEMORY_SCOPE_AGENT) : 0.f; \
  } \
  _Pragma("unroll") \
  for (int k_ = 0; k_ < 4; ++k_){ int idx_ = t + k_ * 512; if (idx_ < CN) (L)[idx_] = tmp_[k_]; } \
} while(0)

// Persistent Sinkhorn: 125 blocks x 512 (16 rows/block, 2 rows/wave x 8 waves),
// fence-free barriers. Each wave holds 2 K-rows + 2 KT-rows in registers; u/v
// exchanged via agent-scope atomics, staged coalesced into LDS per block after
// each barrier. 60 barriers.
__global__ __launch_bounds__(512, 1) void k_sink(
    const float* __restrict__ Km, const float* __restrict__ KTm,
    const int* __restrict__ cv, const int* __restrict__ ci,
    float* __restrict__ u_g, float* __restrict__ v_g,
    float* __restrict__ o0, float* __restrict__ o1,
    float* __restrict__ rconf, float* __restrict__ cconf,
    int* __restrict__ rass, int* __restrict__ cass,
    int* bar){
  __shared__ __attribute__((aligned(16))) float u_lds[2048];
  __shared__ __attribute__((aligned(16))) float v_lds[2048];
  int b = blockIdx.x, t = threadIdx.x, w = t >> 6, l = t & 63;
  int r0 = b * 16 + w * 2, r1 = r0 + 1;
  f32x4 z4 = {0.f, 0.f, 0.f, 0.f};
  f32x4 kA0[8], kA1[8], kT0[8], kT1[8];
  {
    const f32x4* g0 = (const f32x4*)(Km + (size_t)r0 * CN);
    const f32x4* g1 = (const f32x4*)(Km + (size_t)r1 * CN);
    const f32x4* h0 = (const f32x4*)(KTm + (size_t)r0 * CN);
    const f32x4* h1 = (const f32x4*)(KTm + (size_t)r1 * CN);
#pragma unroll
    for (int k = 0; k < 8; ++k){
      int idx = l + k * 64;
      bool ok = idx < 500;
      kA0[k] = ok ? g0[idx] : z4;
      kA1[k] = ok ? g1[idx] : z4;
      kT0[k] = ok ? h0[idx] : z4;
      kT1[k] = ok ? h1[idx] : z4;
    }
  }
  float a0 = (float)cv[r0] / 20000.0f, a1 = (float)cv[r1] / 20000.0f;
  float b0 = (float)ci[r0] / 20000.0f, b1 = (float)ci[r1] / 20000.0f;

  // iteration 0 u-update: v === 1, so Kv = rowsum(K)
  {
    float s0 = 0.f, s1 = 0.f;
#pragma unroll
    for (int k = 0; k < 8; ++k){
      s0 += kA0[k][0] + kA0[k][1] + kA0[k][2] + kA0[k][3];
      s1 += kA1[k][0] + kA1[k][1] + kA1[k][2] + kA1[k][3];
    }
    s0 = wredSum(s0); s1 = wredSum(s1);
    if (l == 0){
      __hip_atomic_store(&u_g[r0], (a0 > 0.f) ? a0 / (s0 + 1e-8f) : 0.f,
                         __ATOMIC_RELAXED, __HIP_MEMORY_SCOPE_AGENT);
      __hip_atomic_store(&u_g[r1], (a1 > 0.f) ? a1 / (s1 + 1e-8f) : 0.f,
                         __ATOMIC_RELAXED, __HIP_MEMORY_SCOPE_AGENT);
    }
  }
  int tgt = 1;
  gbar(bar, tgt); ++tgt;
  STAGE(u_g, u_lds);
  __syncthreads();
  const f32x4* ul4 = (const f32x4*)u_lds;
  const f32x4* vl4 = (const f32x4*)v_lds;

  for (int it = 0; it < 30; ++it){
    // v-update: v = b / (K^T u)
    {
      float s0 = 0.f, s1 = 0.f;
#pragma unroll
      for (int k = 0; k < 8; ++k){
        int idx = l + k * 64;
        if (idx < 500){
          f32x4 x = ul4[idx];
          s0 += kT0[k][0]*x[0] + kT0[k][1]*x[1] + kT0[k][2]*x[2] + kT0[k][3]*x[3];
          s1 += kT1[k][0]*x[0] + kT1[k][1]*x[1] + kT1[k][2]*x[2] + kT1[k][3]*x[3];
        }
      }
      s0 = wredSum(s0); s1 = wredSum(s1);
      if (l == 0){
        __hip_atomic_store(&v_g[r0], (b0 > 0.f) ? b0 / (s0 + 1e-8f) : 0.f,
                           __ATOMIC_RELAXED, __HIP_MEMORY_SCOPE_AGENT);
        __hip_atomic_store(&v_g[r1], (b1 > 0.f) ? b1 / (s1 + 1e-8f) : 0.f,
                           __ATOMIC_RELAXED, __HIP_MEMORY_SCOPE_AGENT);
      }
    }
    gbar(bar, tgt); ++tgt;
    STAGE(v_g, v_lds);
    __syncthreads();
    if (it < 29){
      // u-update: u = a / (K v)
      {
        float s0 = 0.f, s1 = 0.f;
#pragma unroll
        for (int k = 0; k < 8; ++k){
          int idx = l + k * 64;
          if (idx < 500){
            f32x4 x = vl4[idx];
            s0 += kA0[k][0]*x[0] + kA0[k][1]*x[1] + kA0[k][2]*x[2] + kA0[k][3]*x[3];
            s1 += kA1[k][0]*x[0] + kA1[k][1]*x[1] + kA1[k][2]*x[2] + kA1[k][3]*x[3];
          }
        }
        s0 = wredSum(s0); s1 = wredSum(s1);
        if (l == 0){
          __hip_atomic_store(&u_g[r0], (a0 > 0.f) ? a0 / (s0 + 1e-8f) : 0.f,
                             __ATOMIC_RELAXED, __HIP_MEMORY_SCOPE_AGENT);
          __hip_atomic_store(&u_g[r1], (a1 > 0.f) ? a1 / (s1 + 1e-8f) : 0.f,
                             __ATOMIC_RELAXED, __HIP_MEMORY_SCOPE_AGENT);
        }
      }
      gbar(bar, tgt); ++tgt;
      STAGE(u_g, u_lds);
      __syncthreads();
    }
  }
  // row outputs: row_t = u_r*K[r][:]*v[:] / max(u_r*dot(K[r],v),1e-12)
  {
    float s0 = 0.f, s1 = 0.f;
#pragma unroll
    for (int k = 0; k < 8; ++k){
      int idx = l + k * 64;
      if (idx < 500){
        f32x4 x = vl4[idx];
        s0 += kA0[k][0]*x[0] + kA0[k][1]*x[1] + kA0[k][2]*x[2] + kA0[k][3]*x[3];
        s1 += kA1[k][0]*x[0] + kA1[k][1]*x[1] + kA1[k][2]*x[2] + kA1[k][3]*x[3];
      }
    }
    s0 = wredSum(s0); s1 = wredSum(s1);
    float uu0 = u_lds[r0], uu1 = u_lds[r1];
    float f0 = uu0 * (1.f / fmaxf(uu0 * s0, 1e-12f));
    float f1 = uu1 * (1.f / fmaxf(uu1 * s1, 1e-12f));
    float bm0 = -1e30f, bm1 = -1e30f; int bi0 = 1 << 30, bi1 = 1 << 30;
    f32x4* d0 = (f32x4*)(o0 + (size_t)r0 * CN);
    f32x4* d1 = (f32x4*)(o0 + (size_t)r1 * CN);
#pragma unroll
    for (int k = 0; k < 8; ++k){
      int idx = l + k * 64;
      if (idx < 500){
        f32x4 x = vl4[idx];
        f32x4 w0, w1;
#pragma unroll
        for (int q = 0; q < 4; ++q){
          w0[q] = f0 * kA0[k][q] * x[q];
          w1[q] = f1 * kA1[k][q] * x[q];
        }
        d0[idx] = w0; d1[idx] = w1;
#pragma unroll
        for (int q = 0; q < 4; ++q){
          int j = idx * 4 + q;
          if (w0[q] > bm0){ bm0 = w0[q]; bi0 = j; }
          if (w1[q] > bm1){ bm1 = w1[q]; bi1 = j; }
        }
      }
    }
#pragma unroll
    for (int o = 32; o >= 1; o >>= 1){
      float om = __shfl_xor(bm0, o, 64); int oi2 = __shfl_xor(bi0, o, 64);
      if (om > bm0 || (om == bm0 && oi2 < bi0)){ bm0 = om; bi0 = oi2; }
      float om1 = __shfl_xor(bm1, o, 64); int oi3 = __shfl_xor(bi1, o, 64);
      if (om1 > bm1 || (om1 == bm1 && oi3 < bi1)){ bm1 = om1; bi1 = oi3; }
    }
    if (l == 0){ rconf[r0] = bm0; rass[r0] = bi0; rconf[r1] = bm1; rass[r1] = bi1; }
  }
  // col outputs
  {
    float s0 = 0.f, s1 = 0.f;
#pragma unroll
    for (int k = 0; k < 8; ++k){
      int idx = l + k * 64;
      if (idx < 500){
        f32x4 x = ul4[idx];
        s0 += kT0[k][0]*x[0] + kT0[k][1]*x[1] + kT0[k][2]*x[2] + kT0[k][3]*x[3];
        s1 += kT1[k][0]*x[0] + kT1[k][1]*x[1] + kT1[k][2]*x[2] + kT1[k][3]*x[3];
      }
    }
    s0 = wredSum(s0); s1 = wredSum(s1);
    float vv0 = v_lds[r0], vv1 = v_lds[r1];
    float f0 = vv0 * (1.f / fmaxf(vv0 * s0, 1e-12f));
    float f1 = vv1 * (1.f / fmaxf(vv1 * s1, 1e-12f));
    float bm0 = -1e30f, bm1 = -1e30f; int bi0 = 1 << 30, bi1 = 1 << 30;
    f32x4* d0 = (f32x4*)(o1 + (size_t)r0 * CN);
    f32x4* d1 = (f32x4*)(o1 + (size_t)r1 * CN);
#pragma unroll
    for (int k = 0; k < 8; ++k){
      int idx = l + k * 64;
      if (idx < 500){
        f32x4 x = ul4[idx];
        f32x4 w0, w1;
#pragma unroll
        for (int q = 0; q < 4; ++q){
          w0[q] = f0 * kT0[k][q] * x[q];
          w1[q] = f1 * kT1[k][q] * x[q];
        }
        d0[idx] = w0; d1[idx] = w1;
#pragma unroll
        for (int q = 0; q < 4; ++q){
          int j = idx * 4 + q;
          if (w0[q] > bm0){ bm0 = w0[q]; bi0 = j; }
          if (w1[q] > bm1){ bm1 = w1[q]; bi1 = j; }
        }
      }
    }
#pragma unroll
    for (int o = 32; o >= 1; o >>= 1){
      float om = __shfl_xor(bm0, o, 64); int oi2 = __shfl_xor(bi0, o, 64);
      if (om > bm0 || (om == bm0 && oi2 < bi0)){ bm0 = om; bi0 = oi2; }
      float om1 = __shfl_xor(bm1, o, 64); int oi3 = __shfl_xor(bi1, o, 64);
      if (om1 > bm1 || (om1 == bm1 && oi3 < bi1)){ bm1 = om1; bi1 = oi3; }
    }
    if (l == 0){ cconf[r0] = bm0; cass[r0] = bi0; cconf[r1] = bm1; cass[r1] = bi1; }
  }
}

// Merged fill + topk: one block per row i. Zeros o2..o5 rows, writes common/
// specific, then scatters row-topk into o4 and col-topk into o5.
__global__ __launch_bounds__(256) void k_post(const float* __restrict__ rt, const float* __restrict__ ct,
    const int* __restrict__ cv, const int* __restrict__ ci,
    const float* __restrict__ rc, const float* __restrict__ cc,
    const int* __restrict__ ra, const int* __restrict__ ca,
    float* o2, float* o3, float* o4, float* o5){
  __shared__ float sv[256 * 3];
  __shared__ int si[256 * 3];
  int i = blockIdx.x, t = threadIdx.x;
  bool av = cv[i] > 0, ai = ci[i] > 0;
  float rcv = rc[i], ccv = cc[i];
  int aidx = ra[i];
  bool high = av && (rcv >= 0.55f);
  bool cm = high && (ca[aidx] == i);
  bool sp = high && !cm;
  bool remr = av && (rcv >= 0.25f) && (rcv < 0.55f);
  bool remc = ai && (ccv >= 0.25f) && (ccv < 0.55f);
  f32x4 z = {0.f, 0.f, 0.f, 0.f};
  f32x4* p2 = (f32x4*)(o2 + (size_t)i * CN);
  f32x4* p3 = (f32x4*)(o3 + (size_t)i * CN);
  f32x4* p4 = (f32x4*)(o4 + (size_t)i * CN);
  f32x4* p5 = (f32x4*)(o5 + (size_t)i * CN);
  const f32x4* rp = (const f32x4*)(rt + (size_t)i * CN);
  for (int c = t; c < 500; c += 256){
    p2[c] = z;
    p3[c] = sp ? rp[c] : z;
    p4[c] = z;
    p5[c] = z;
  }
  __syncthreads();
  if (t == 0 && cm) o2[(size_t)i * CN + aidx] = rcv;
  for (int pass = 0; pass < 2; ++pass){
    bool run = pass ? remc : remr;
    if (!run) continue;
    const float* M = pass ? ct : rt;
    float* o = pass ? o5 : o4;
    float v0 = -1.f, v1 = -1.f, v2 = -1.f;
    int i0 = 1 << 30, i1 = 1 << 30, i2 = 1 << 30;
    for (int k = 0; k < 8; ++k){
      int j = t + k * 256;
      if (j >= CN) break;
      float val = M[(size_t)i * CN + j];
      if (val > v0 || (val == v0 && j < i0)){ v2=v1; i2=i1; v1=v0; i1=i0; v0=val; i0=j; }
      else if (val > v1 || (val == v1 && j < i1)){ v2=v1; i2=i1; v1=val; i1=j; }
      else if (val > v2 || (val == v2 && j < i2)){ v2=val; i2=j; }
    }
    sv[t*3+0]=v0; sv[t*3+1]=v1; sv[t*3+2]=v2;
    si[t*3+0]=i0; si[t*3+1]=i1; si[t*3+2]=i2;
    __syncthreads();
    if (t == 0){
      float w0=-1.f, w1=-1.f, w2=-1.f; int j0=1<<30, j1=1<<30, j2=1<<30;
      for (int q = 0; q < 256 * 3; ++q){
        float val = sv[q]; int j = si[q];
        if (j >= CN) continue;
        if (val > w0 || (val == w0 && j < j0)){ w2=w1; j2=j1; w1=w0; j1=j0; w0=val; j0=j; }
        else if (val > w1 || (val == w1 && j < j1)){ w2=w1; j2=j1; w1=val; j1=j; }
        else if (val > w2 || (val == w2 && j < j2)){ w2=val; j2=j; }
      }
      o[(size_t)i * CN + j0] = w0;
      o[(size_t)i * CN + j1] = w1;
      o[(size_t)i * CN + j2] = w2;
    }
    __syncthreads();
  }
}

extern "C" void kernel_launch(void* const* d_in, const int* in_sizes, int n_in,
                              void* d_out, int out_size, void* d_ws, size_t ws_size,
                              hipStream_t stream){
  (void)in_sizes; (void)n_in; (void)out_size; (void)ws_size;
  const float* visl = (const float*)d_in[0];
  const float* irl  = (const float*)d_in[1];
  const float* vm   = (const float*)d_in[2];
  const float* im   = (const float*)d_in[3];
  const int* rgb    = (const int*)d_in[4];
  const int* iri    = (const int*)d_in[5];
  float* out = (float*)d_out;
  float* o0 = out;                 // Km  -> row_t (in place)
  float* o1 = out + 4000000;       // imb(bf16) -> KTm -> col_t (in place)
  float* o2 = out + 8000000;       // proto_v -> common_rm
  float* o3 = out + 12000000;      // proto_i -> specific_rm
  float* o4 = out + 16000000;      // E -> remain_rm
  float* o5 = out + 20000000;      // vmb(bf16) -> remain_col_rm
  char* sm = (char*)d_ws;
  float* ev   = (float*)(sm + 0);
  float* ei   = (float*)(sm + 8000);
  float* rv   = (float*)(sm + 16000);
  float* ri   = (float*)(sm + 24000);
  float* uvec = (float*)(sm + 32000);
  float* vvec = (float*)(sm + 40000);
  int* bar    = (int*)(sm + 48000);   // [0]=root, [32]=gen, [64+g*32]=groups
  float* rconf= (float*)(sm + 64000);
  float* cconf= (float*)(sm + 72000);
  int* rass = (int*)(sm + 80000);
  int* cass = (int*)(sm + 88000);
  int* cv   = (int*)(sm + 96000);
  int* ci   = (int*)(sm + 104000);
  int* ov   = (int*)(sm + 112000);
  int* oi   = (int*)(sm + 120000);
  int* curv = (int*)(sm + 128000);
  int* curi = (int*)(sm + 136000);
  int* ordv = (int*)(sm + 176000);
  int* ordi = (int*)(sm + 256000);
  unsigned short* vmb = (unsigned short*)o5;   // dead until k_post
  unsigned short* imb = (unsigned short*)o1;   // dead until k_tr (after gemm2)

  k_zero<<<47, 256, 0, stream>>>(cv, 12000, bar);  // cv..curi contiguous + barrier vars
  k_hist<<<157, 256, 0, stream>>>(rgb, iri, cv, ci);
  k_scan<<<1, 1024, 0, stream>>>(cv, ci, ov, oi);
  k_scatter<<<157, 256, 0, stream>>>(rgb, iri, ov, oi, curv, curi, ordv, ordi);
  k_class<<<2 * CN + 1000, 256, 0, stream>>>(visl, irl, cv, ci, ov, oi, ordv, ordi,
                                             o2, o3, ev, ei, vm, im, vmb, imb, rv, ri);
  k_prep<<<dim3(32, 32), 256, 0, stream>>>(o2, o3, ev, ei, cv, ci, o4);
  k_gemm2<<<dim3(16, 16), 256, 0, stream>>>(vmb, imb, rv, ri, o4, o0);
  k_tr<<<dim3(32, 32), 256, 0, stream>>>(o0, o1);
  k_sink<<<NBLK, 512, 0, stream>>>(o0, o1, cv, ci, uvec, vvec, o0, o1,
                                   rconf, cconf, rass, cass, bar);
  k_post<<<CN, 256, 0, stream>>>(o0, o1, cv, ci, rconf, cconf, rass, cass, o2, o3, o4, o5);
}